// Round 6
// baseline (214.980 us; speedup 1.0000x reference)
//
#include <hip/hip_runtime.h>
#include <math.h>

#define N_RAYS 65536
#define T_SAMPLES 128
#define HID 16

#define RAYS_PER_BLOCK 64
#define CHUNKS 8
#define CHUNK_LEN (T_SAMPLES / CHUNKS)   // 16 samples -> 8 pairs

#define L2E 1.4426950408889634f

typedef float v2f __attribute__((ext_vector_type(2)));

// 8 waves/block (512 thr), 8 waves/EU min -> VGPR cap 64 (current use ~52).
// 1024 blocks x 8 waves = 8192 waves; LDS 33KB -> 4 blocks/CU -> 32 waves/CU
// = 100% occupancy cap (was 50% at CHUNKS=4). Kernel is latency-bound
// (VALUBusy ~60% invariant under big VALU-count changes), so resident-wave
// count is the lever.
__global__ __launch_bounds__(512, 8) void radiance_kernel(
    const float* __restrict__ o,
    const float* __restrict__ d,
    const float* __restrict__ tnear,
    const float* __restrict__ tfar,
    const float* __restrict__ noise,
    const float* __restrict__ W1,
    const float* __restrict__ b1,
    const float* __restrict__ w_sigma,
    const float* __restrict__ W_rgb,
    float* __restrict__ out)
{
    __shared__ __align__(16) float s_noise[(T_SAMPLES + 1) * RAYS_PER_BLOCK]; // 33 KB

    const int lane  = threadIdx.x & 63;
    const int chunk = threadIdx.x >> 6;   // 0..7
    const int ray0  = blockIdx.x * RAYS_PER_BLOCK;
    const int ray   = ray0 + lane;

    // ---- stage noise window (coalesced float4), sentinel row = 0 ----
    {
        float4* s4 = (float4*)s_noise;
#pragma unroll
        for (int k = 0; k < 4; ++k) {
            const int linear = k * 512 + threadIdx.x;   // float4 index in window
            const int t  = linear >> 4;                 // 16 float4 per row
            const int c4 = linear & 15;
            s4[t * 16 + c4] =
                *(const float4*)(noise + (size_t)t * N_RAYS + ray0 + c4 * 4);
        }
        if (threadIdx.x < 16)
            s4[T_SAMPLES * 16 + threadIdx.x] = make_float4(0.f, 0.f, 0.f, 0.f);
    }

    // ---- per-ray setup (duplicated across the 8 chunk-waves) ----
    const float ox = o[ray*3+0], oy = o[ray*3+1], oz = o[ray*3+2];
    const float dx = d[ray*3+0], dy = d[ray*3+1], dz = d[ray*3+2];
    const float tn = tnear[ray];
    const float tf = tfar[ray];
    const float dnorm = sqrtf(dx*dx + dy*dy + dz*dz);
    const float sc = (tf - tn) * (1.0f / (float)T_SAMPLES);

    float A[HID], B[HID];
#pragma unroll
    for (int j = 0; j < HID; ++j) {
        const float w0 = W1[0*HID + j], w1 = W1[1*HID + j], w2 = W1[2*HID + j];
        A[j] = fmaf(ox, w0, fmaf(oy, w1, fmaf(oz, w2, b1[j])));
        B[j] = fmaf(dx, w0, fmaf(dy, w1, dz * w2));
    }
    float WS[HID], WR[HID], WG[HID], WB[HID];
#pragma unroll
    for (int j = 0; j < HID; ++j) {
        WS[j] = w_sigma[j];
        WR[j] = W_rgb[j*3+0];
        WG[j] = W_rgb[j*3+1];
        WB[j] = W_rgb[j*3+2];
    }

    __syncthreads();   // noise window ready

    const int t0 = chunk * CHUNK_LEN;
    const float* s_row = s_noise + (size_t)t0 * RAYS_PER_BLOCK + lane;
    float ts = fmaf(sc, (float)t0 + s_row[0], tn);

    float lt = 1.0f;
    float cr = 0.f, cg = 0.f, cb = 0.f, cd = 0.f, ca = 0.f;

#pragma unroll 2
    for (int p = 0; p < CHUNK_LEN / 2; ++p) {
        const int i = 2 * p;
        // sample positions: ts (=t0+i), tsb (=t0+i+1), tsc (=t0+i+2)
        // last chunk's last pair reads sentinel row 128 (=0) -> tsc = tn+sc*128 = tf
        const float nzb = s_row[(i + 1) * RAYS_PER_BLOCK];
        const float nzc = s_row[(i + 2) * RAYS_PER_BLOCK];
        const float tsb = fmaf(sc, (float)(t0 + i + 1) + nzb, tn);
        const float tsc = fmaf(sc, (float)(t0 + i + 2) + nzc, tn);

        // ---- packed MLP for the two samples (v_pk_fma_f32) ----
        const v2f ts2 = {ts, tsb};
        v2f sp2 = {0.f, 0.f}, rr2 = {0.f, 0.f}, gg2 = {0.f, 0.f}, bb2 = {0.f, 0.f};
#pragma unroll
        for (int j = 0; j < HID; ++j) {
            v2f h2 = __builtin_elementwise_fma(ts2, (v2f){B[j], B[j]}, (v2f){A[j], A[j]});
            h2 = __builtin_elementwise_max(h2, (v2f){0.f, 0.f});
            sp2 = __builtin_elementwise_fma(h2, (v2f){WS[j], WS[j]}, sp2);
            rr2 = __builtin_elementwise_fma(h2, (v2f){WR[j], WR[j]}, rr2);
            gg2 = __builtin_elementwise_fma(h2, (v2f){WG[j], WG[j]}, gg2);
            bb2 = __builtin_elementwise_fma(h2, (v2f){WB[j], WB[j]}, bb2);
        }

        // ---- softplus -> l2 = log2(1+exp(sp)) for both samples ----
        const v2f msp2 = __builtin_elementwise_abs(sp2) * (v2f){-L2E, -L2E};
        const float ea = __builtin_amdgcn_exp2f(msp2.x);
        const float eb = __builtin_amdgcn_exp2f(msp2.y);
        const v2f lg2 = {__builtin_amdgcn_logf(1.0f + ea), __builtin_amdgcn_logf(1.0f + eb)};
        const v2f l2_2 = __builtin_elementwise_fma(
            __builtin_elementwise_max(sp2, (v2f){0.f, 0.f}), (v2f){L2E, L2E}, lg2);

        // ---- et = 2^(-delta*dnorm*l2) for both samples ----
        const v2f delta2 = {tsb - ts, tsc - tsb};
        const v2f arg2 = (delta2 * (v2f){-dnorm, -dnorm}) * l2_2;
        const float et_a = __builtin_amdgcn_exp2f(arg2.x);
        const float et_b = __builtin_amdgcn_exp2f(arg2.y);

        // ---- sigmoids (packed pre-mul, scalar exp2/rcp) ----
        const v2f nrr2 = rr2 * (v2f){-L2E, -L2E};
        const v2f ngg2 = gg2 * (v2f){-L2E, -L2E};
        const v2f nbb2 = bb2 * (v2f){-L2E, -L2E};
        const float r_a = __builtin_amdgcn_rcpf(1.0f + __builtin_amdgcn_exp2f(nrr2.x));
        const float r_b = __builtin_amdgcn_rcpf(1.0f + __builtin_amdgcn_exp2f(nrr2.y));
        const float g_a = __builtin_amdgcn_rcpf(1.0f + __builtin_amdgcn_exp2f(ngg2.x));
        const float g_b = __builtin_amdgcn_rcpf(1.0f + __builtin_amdgcn_exp2f(ngg2.y));
        const float b_a = __builtin_amdgcn_rcpf(1.0f + __builtin_amdgcn_exp2f(nbb2.x));
        const float b_b = __builtin_amdgcn_rcpf(1.0f + __builtin_amdgcn_exp2f(nbb2.y));

        // ---- serial integration, sample a then b ----
        {
            const float w = lt * (1.0f - et_a);
            cr = fmaf(w, r_a, cr);
            cg = fmaf(w, g_a, cg);
            cb = fmaf(w, b_a, cb);
            cd = fmaf(w, ts, cd);
            ca += w;
            lt *= et_a;
        }
        {
            const float w = lt * (1.0f - et_b);
            cr = fmaf(w, r_b, cr);
            cg = fmaf(w, g_b, cg);
            cb = fmaf(w, b_b, cb);
            cd = fmaf(w, tsb, cd);
            ca += w;
            lt *= et_b;
        }
        ts = tsc;
    }

    // ---- combine chunks (overlay on noise arena) ----
    __syncthreads();
    float* s_lt  = s_noise;                           // [CHUNKS][64]
    float* s_acc = s_noise + CHUNKS * RAYS_PER_BLOCK; // [CHUNKS][5][64]
    s_lt[chunk * 64 + lane] = lt;
    s_acc[(chunk * 5 + 0) * 64 + lane] = cr;
    s_acc[(chunk * 5 + 1) * 64 + lane] = cg;
    s_acc[(chunk * 5 + 2) * 64 + lane] = cb;
    s_acc[(chunk * 5 + 3) * 64 + lane] = cd;
    s_acc[(chunk * 5 + 4) * 64 + lane] = ca;
    __syncthreads();

    if (chunk == 0) {
        float scale = 1.0f;
        float a0 = 0.f, a1 = 0.f, a2 = 0.f, a3 = 0.f, a4 = 0.f;
#pragma unroll
        for (int c = 0; c < CHUNKS; ++c) {
            a0 = fmaf(scale, s_acc[(c * 5 + 0) * 64 + lane], a0);
            a1 = fmaf(scale, s_acc[(c * 5 + 1) * 64 + lane], a1);
            a2 = fmaf(scale, s_acc[(c * 5 + 2) * 64 + lane], a2);
            a3 = fmaf(scale, s_acc[(c * 5 + 3) * 64 + lane], a3);
            a4 = fmaf(scale, s_acc[(c * 5 + 4) * 64 + lane], a4);
            scale *= s_lt[c * 64 + lane];
        }
        out[ray*5+0] = a0;
        out[ray*5+1] = a1;
        out[ray*5+2] = a2;
        out[ray*5+3] = a3;
        out[ray*5+4] = a4;
    }
}

extern "C" void kernel_launch(void* const* d_in, const int* in_sizes, int n_in,
                              void* d_out, int out_size, void* d_ws, size_t ws_size,
                              hipStream_t stream) {
    const float* o       = (const float*)d_in[0];
    const float* d       = (const float*)d_in[1];
    const float* tnear   = (const float*)d_in[2];
    const float* tfar    = (const float*)d_in[3];
    const float* noise   = (const float*)d_in[4];
    const float* W1      = (const float*)d_in[5];
    const float* b1      = (const float*)d_in[6];
    const float* w_sigma = (const float*)d_in[7];
    const float* W_rgb   = (const float*)d_in[8];
    float* out = (float*)d_out;

    dim3 block(64 * CHUNKS);                       // 512
    dim3 grid(N_RAYS / RAYS_PER_BLOCK);            // 1024
    hipLaunchKernelGGL(radiance_kernel, grid, block, 0, stream,
                       o, d, tnear, tfar, noise, W1, b1, w_sigma, W_rgb, out);
}

// Round 7
// 116.554 us; speedup vs baseline: 1.8445x; 1.8445x over previous
//
#include <hip/hip_runtime.h>
#include <math.h>

#define N_RAYS 65536
#define T_SAMPLES 128
#define HID 16

#define RAYS_PER_BLOCK 32
#define CHUNKS 8
#define CHUNK_LEN (T_SAMPLES / CHUNKS)   // 16 samples -> 8 pairs

#define L2E 1.4426950408889634f

typedef float v2f __attribute__((ext_vector_type(2)));

// block=256 (32 rays x 8 chunks), launch_bounds(256,4) -> VGPR cap 128
// (known-good: 52 used, no spill). Grid 2048 blocks -> 8 blocks/CU;
// LDS 16.5 KB -> 9-block limit; VGPR 52 -> 8 waves/SIMD. Net: 32 waves/CU
// (was 16). R5's (512,8) spill disaster: never cap VGPR below ~80 here.
__global__ __launch_bounds__(256, 4) void radiance_kernel(
    const float* __restrict__ o,
    const float* __restrict__ d,
    const float* __restrict__ tnear,
    const float* __restrict__ tfar,
    const float* __restrict__ noise,
    const float* __restrict__ W1,
    const float* __restrict__ b1,
    const float* __restrict__ w_sigma,
    const float* __restrict__ W_rgb,
    float* __restrict__ out)
{
    // rows of 32 floats (128 B); wave spans 2 rows -> 2-way bank alias (free)
    __shared__ __align__(16) float s_noise[(T_SAMPLES + 1) * RAYS_PER_BLOCK]; // 16.5 KB

    const int ridx  = threadIdx.x & 31;   // ray within block
    const int chunk = threadIdx.x >> 5;   // 0..7
    const int ray0  = blockIdx.x * RAYS_PER_BLOCK;
    const int ray   = ray0 + ridx;

    // ---- stage noise window (float4, 4 per thread), sentinel row = 0 ----
    {
        float4* s4 = (float4*)s_noise;
#pragma unroll
        for (int k = 0; k < 4; ++k) {
            const int linear = k * 256 + threadIdx.x;   // 0..1023 float4 slots
            const int t  = linear >> 3;                 // 8 float4 per row
            const int c4 = linear & 7;
            s4[t * 8 + c4] =
                *(const float4*)(noise + (size_t)t * N_RAYS + ray0 + c4 * 4);
        }
        if (threadIdx.x < 8)
            s4[T_SAMPLES * 8 + threadIdx.x] = make_float4(0.f, 0.f, 0.f, 0.f);
    }

    // ---- per-ray setup (duplicated across the 8 chunk-groups) ----
    const float ox = o[ray*3+0], oy = o[ray*3+1], oz = o[ray*3+2];
    const float dx = d[ray*3+0], dy = d[ray*3+1], dz = d[ray*3+2];
    const float tn = tnear[ray];
    const float tf = tfar[ray];
    const float dnorm = sqrtf(dx*dx + dy*dy + dz*dz);
    const float sc = (tf - tn) * (1.0f / (float)T_SAMPLES);

    float A[HID], B[HID];
#pragma unroll
    for (int j = 0; j < HID; ++j) {
        const float w0 = W1[0*HID + j], w1 = W1[1*HID + j], w2 = W1[2*HID + j];
        A[j] = fmaf(ox, w0, fmaf(oy, w1, fmaf(oz, w2, b1[j])));
        B[j] = fmaf(dx, w0, fmaf(dy, w1, dz * w2));
    }
    float WS[HID], WR[HID], WG[HID], WB[HID];
#pragma unroll
    for (int j = 0; j < HID; ++j) {
        WS[j] = w_sigma[j];
        WR[j] = W_rgb[j*3+0];
        WG[j] = W_rgb[j*3+1];
        WB[j] = W_rgb[j*3+2];
    }

    __syncthreads();   // noise window ready

    const int t0 = chunk * CHUNK_LEN;
    const float* s_row = s_noise + (size_t)t0 * RAYS_PER_BLOCK + ridx;
    float ts = fmaf(sc, (float)t0 + s_row[0], tn);

    float lt = 1.0f;
    float cr = 0.f, cg = 0.f, cb = 0.f, cd = 0.f, ca = 0.f;

#pragma unroll 2
    for (int p = 0; p < CHUNK_LEN / 2; ++p) {
        const int i = 2 * p;
        // last chunk's last pair reads sentinel row 128 (=0) -> tsc = tn+sc*128 = tf
        const float nzb = s_row[(i + 1) * RAYS_PER_BLOCK];
        const float nzc = s_row[(i + 2) * RAYS_PER_BLOCK];
        const float tsb = fmaf(sc, (float)(t0 + i + 1) + nzb, tn);
        const float tsc = fmaf(sc, (float)(t0 + i + 2) + nzc, tn);

        // ---- packed MLP for the two samples (v_pk_fma_f32) ----
        const v2f ts2 = {ts, tsb};
        v2f sp2 = {0.f, 0.f}, rr2 = {0.f, 0.f}, gg2 = {0.f, 0.f}, bb2 = {0.f, 0.f};
#pragma unroll
        for (int j = 0; j < HID; ++j) {
            v2f h2 = __builtin_elementwise_fma(ts2, (v2f){B[j], B[j]}, (v2f){A[j], A[j]});
            h2 = __builtin_elementwise_max(h2, (v2f){0.f, 0.f});
            sp2 = __builtin_elementwise_fma(h2, (v2f){WS[j], WS[j]}, sp2);
            rr2 = __builtin_elementwise_fma(h2, (v2f){WR[j], WR[j]}, rr2);
            gg2 = __builtin_elementwise_fma(h2, (v2f){WG[j], WG[j]}, gg2);
            bb2 = __builtin_elementwise_fma(h2, (v2f){WB[j], WB[j]}, bb2);
        }

        // ---- softplus -> l2 = log2(1+exp(sp)) for both samples ----
        const v2f msp2 = __builtin_elementwise_abs(sp2) * (v2f){-L2E, -L2E};
        const float ea = __builtin_amdgcn_exp2f(msp2.x);
        const float eb = __builtin_amdgcn_exp2f(msp2.y);
        const v2f lg2 = {__builtin_amdgcn_logf(1.0f + ea), __builtin_amdgcn_logf(1.0f + eb)};
        const v2f l2_2 = __builtin_elementwise_fma(
            __builtin_elementwise_max(sp2, (v2f){0.f, 0.f}), (v2f){L2E, L2E}, lg2);

        // ---- et = 2^(-delta*dnorm*l2) ----
        const v2f delta2 = {tsb - ts, tsc - tsb};
        const v2f arg2 = (delta2 * (v2f){-dnorm, -dnorm}) * l2_2;
        const float et_a = __builtin_amdgcn_exp2f(arg2.x);
        const float et_b = __builtin_amdgcn_exp2f(arg2.y);

        // ---- sigmoids ----
        const v2f nrr2 = rr2 * (v2f){-L2E, -L2E};
        const v2f ngg2 = gg2 * (v2f){-L2E, -L2E};
        const v2f nbb2 = bb2 * (v2f){-L2E, -L2E};
        const float r_a = __builtin_amdgcn_rcpf(1.0f + __builtin_amdgcn_exp2f(nrr2.x));
        const float r_b = __builtin_amdgcn_rcpf(1.0f + __builtin_amdgcn_exp2f(nrr2.y));
        const float g_a = __builtin_amdgcn_rcpf(1.0f + __builtin_amdgcn_exp2f(ngg2.x));
        const float g_b = __builtin_amdgcn_rcpf(1.0f + __builtin_amdgcn_exp2f(ngg2.y));
        const float b_a = __builtin_amdgcn_rcpf(1.0f + __builtin_amdgcn_exp2f(nbb2.x));
        const float b_b = __builtin_amdgcn_rcpf(1.0f + __builtin_amdgcn_exp2f(nbb2.y));

        // ---- serial integration ----
        {
            const float w = lt * (1.0f - et_a);
            cr = fmaf(w, r_a, cr);
            cg = fmaf(w, g_a, cg);
            cb = fmaf(w, b_a, cb);
            cd = fmaf(w, ts, cd);
            ca += w;
            lt *= et_a;
        }
        {
            const float w = lt * (1.0f - et_b);
            cr = fmaf(w, r_b, cr);
            cg = fmaf(w, g_b, cg);
            cb = fmaf(w, b_b, cb);
            cd = fmaf(w, tsb, cd);
            ca += w;
            lt *= et_b;
        }
        ts = tsc;
    }

    // ---- combine chunks (overlay on noise arena) ----
    __syncthreads();
    float* s_lt  = s_noise;                             // [8][32]
    float* s_acc = s_noise + CHUNKS * RAYS_PER_BLOCK;   // [8][5][32]
    s_lt[chunk * RAYS_PER_BLOCK + ridx] = lt;
    s_acc[(chunk * 5 + 0) * RAYS_PER_BLOCK + ridx] = cr;
    s_acc[(chunk * 5 + 1) * RAYS_PER_BLOCK + ridx] = cg;
    s_acc[(chunk * 5 + 2) * RAYS_PER_BLOCK + ridx] = cb;
    s_acc[(chunk * 5 + 3) * RAYS_PER_BLOCK + ridx] = cd;
    s_acc[(chunk * 5 + 4) * RAYS_PER_BLOCK + ridx] = ca;
    __syncthreads();

    if (threadIdx.x < RAYS_PER_BLOCK) {
        float scale = 1.0f;
        float a0 = 0.f, a1 = 0.f, a2 = 0.f, a3 = 0.f, a4 = 0.f;
#pragma unroll
        for (int c = 0; c < CHUNKS; ++c) {
            a0 = fmaf(scale, s_acc[(c * 5 + 0) * RAYS_PER_BLOCK + ridx], a0);
            a1 = fmaf(scale, s_acc[(c * 5 + 1) * RAYS_PER_BLOCK + ridx], a1);
            a2 = fmaf(scale, s_acc[(c * 5 + 2) * RAYS_PER_BLOCK + ridx], a2);
            a3 = fmaf(scale, s_acc[(c * 5 + 3) * RAYS_PER_BLOCK + ridx], a3);
            a4 = fmaf(scale, s_acc[(c * 5 + 4) * RAYS_PER_BLOCK + ridx], a4);
            scale *= s_lt[c * RAYS_PER_BLOCK + ridx];
        }
        out[ray*5+0] = a0;
        out[ray*5+1] = a1;
        out[ray*5+2] = a2;
        out[ray*5+3] = a3;
        out[ray*5+4] = a4;
    }
}

extern "C" void kernel_launch(void* const* d_in, const int* in_sizes, int n_in,
                              void* d_out, int out_size, void* d_ws, size_t ws_size,
                              hipStream_t stream) {
    const float* o       = (const float*)d_in[0];
    const float* d       = (const float*)d_in[1];
    const float* tnear   = (const float*)d_in[2];
    const float* tfar    = (const float*)d_in[3];
    const float* noise   = (const float*)d_in[4];
    const float* W1      = (const float*)d_in[5];
    const float* b1      = (const float*)d_in[6];
    const float* w_sigma = (const float*)d_in[7];
    const float* W_rgb   = (const float*)d_in[8];
    float* out = (float*)d_out;

    dim3 block(RAYS_PER_BLOCK * CHUNKS);           // 256
    dim3 grid(N_RAYS / RAYS_PER_BLOCK);            // 2048
    hipLaunchKernelGGL(radiance_kernel, grid, block, 0, stream,
                       o, d, tnear, tfar, noise, W1, b1, w_sigma, W_rgb, out);
}